// Round 1
// baseline (1255.840 us; speedup 1.0000x reference)
//
#include <hip/hip_runtime.h>

// GRFExactAttention — f32 baseline, 5-stage pipeline.
// B=8 N=1024 C=768 H=12 D=64. All inputs/outputs f32.
//
// ws layout (floats): [0]=q' [S]=k' [2S]=v [3S]=q_s [4S]=k_s ; attn reuses q'.
// S = 8192*768 = 6291456 floats. Total 5S*4 = 125.8 MB.

#define B_ 8
#define N_ 1024
#define C_ 768
#define H_ 12
#define D_ 64
#define BN_ (B_ * N_)
#define C3_ (3 * C_)
#define EPS_ 1e-6f

// ---------------------------------------------------------------------------
// Stage 1: qkv = x @ w_qkv ; split into q'(relu+eps), k'(relu+eps), v
// 64x64 tile, 256 thr, 4x4 microtile, K-chunk 16.
// ---------------------------------------------------------------------------
__global__ __launch_bounds__(256) void k_qkv(const float* __restrict__ x,
                                             const float* __restrict__ w,
                                             float* __restrict__ qb,
                                             float* __restrict__ kb,
                                             float* __restrict__ vb)
{
    __shared__ float As[16][68];  // As[k][m]
    __shared__ float Bs[16][68];  // Bs[k][n]
    const int tid = threadIdx.x;
    const int ty = tid >> 4, tx = tid & 15;
    const int m0 = blockIdx.y * 64;
    const int n0 = blockIdx.x * 64;
    const int lrA = tid >> 2, lqA = (tid & 3) * 4;
    const int lrB = tid >> 4, lcB = (tid & 15) * 4;
    float acc[4][4] = {};
    for (int k0 = 0; k0 < C_; k0 += 16) {
        float4 a4 = *reinterpret_cast<const float4*>(&x[(size_t)(m0 + lrA) * C_ + k0 + lqA]);
        float4 b4 = *reinterpret_cast<const float4*>(&w[(size_t)(k0 + lrB) * C3_ + n0 + lcB]);
        __syncthreads();
        As[lqA + 0][lrA] = a4.x;
        As[lqA + 1][lrA] = a4.y;
        As[lqA + 2][lrA] = a4.z;
        As[lqA + 3][lrA] = a4.w;
        *reinterpret_cast<float4*>(&Bs[lrB][lcB]) = b4;
        __syncthreads();
#pragma unroll
        for (int kk = 0; kk < 16; ++kk) {
            float4 av = *reinterpret_cast<const float4*>(&As[kk][ty * 4]);
            float4 bv = *reinterpret_cast<const float4*>(&Bs[kk][tx * 4]);
            float a_[4] = {av.x, av.y, av.z, av.w};
            float b_[4] = {bv.x, bv.y, bv.z, bv.w};
#pragma unroll
            for (int i = 0; i < 4; ++i)
#pragma unroll
                for (int j = 0; j < 4; ++j)
                    acc[i][j] = fmaf(a_[i], b_[j], acc[i][j]);
        }
    }
#pragma unroll
    for (int i = 0; i < 4; ++i) {
        const int r = m0 + ty * 4 + i;
#pragma unroll
        for (int j = 0; j < 4; ++j) {
            const int c = n0 + tx * 4 + j;
            const int seg = c / C_;
            const int cc = c - seg * C_;
            float v = acc[i][j];
            if (seg < 2) v = fmaxf(v, 0.f) + EPS_;
            float* dst = (seg == 0) ? qb : ((seg == 1) ? kb : vb);
            dst[(size_t)r * C_ + cc] = v;
        }
    }
}

// ---------------------------------------------------------------------------
// Stage 2/3: dst[b,m,c] = src[b,m,c] + 0.1 * sum_n mask[n,m] * src[b,n,c]
// A = mask^T (load is contiguous in m), B = src_b. M=1024 N=768 K=1024.
// ---------------------------------------------------------------------------
__global__ __launch_bounds__(256) void k_smooth(const float* __restrict__ mask,
                                                const float* __restrict__ src,
                                                float* __restrict__ dst)
{
    __shared__ float As[16][68];  // As[k][m] = mask[k][m]
    __shared__ float Bs[16][68];  // Bs[k][c]
    const int tid = threadIdx.x;
    const int ty = tid >> 4, tx = tid & 15;
    const int m0 = blockIdx.y * 64;
    const int c0 = blockIdx.x * 64;
    const int b = blockIdx.z;
    const float* srcb = src + (size_t)b * N_ * C_;
    const int lr = tid >> 4, lc = (tid & 15) * 4;
    float acc[4][4] = {};
    for (int k0 = 0; k0 < N_; k0 += 16) {
        float4 a4 = *reinterpret_cast<const float4*>(&mask[(size_t)(k0 + lr) * N_ + m0 + lc]);
        float4 b4 = *reinterpret_cast<const float4*>(&srcb[(size_t)(k0 + lr) * C_ + c0 + lc]);
        __syncthreads();
        *reinterpret_cast<float4*>(&As[lr][lc]) = a4;
        *reinterpret_cast<float4*>(&Bs[lr][lc]) = b4;
        __syncthreads();
#pragma unroll
        for (int kk = 0; kk < 16; ++kk) {
            float4 av = *reinterpret_cast<const float4*>(&As[kk][ty * 4]);
            float4 bv = *reinterpret_cast<const float4*>(&Bs[kk][tx * 4]);
            float a_[4] = {av.x, av.y, av.z, av.w};
            float b_[4] = {bv.x, bv.y, bv.z, bv.w};
#pragma unroll
            for (int i = 0; i < 4; ++i)
#pragma unroll
                for (int j = 0; j < 4; ++j)
                    acc[i][j] = fmaf(a_[i], b_[j], acc[i][j]);
        }
    }
#pragma unroll
    for (int i = 0; i < 4; ++i) {
        const int m = m0 + ty * 4 + i;
#pragma unroll
        for (int j = 0; j < 4; ++j) {
            const int c = c0 + tx * 4 + j;
            dst[(size_t)b * N_ * C_ + (size_t)m * C_ + c] =
                srcb[(size_t)m * C_ + c] + 0.1f * acc[i][j];
        }
    }
}

// ---------------------------------------------------------------------------
// Stage 4: fused masked linear attention per (b,h).
// out[n,d] = z_n * sum_m (q_s[n,:]·k_s[m,:]) * mask[n,m] * v[m,d]
// z_n = 1/(sum_m (...)*mask[n,m] + eps)
// Block: 64 query rows; loop over 16 key tiles of 64.
// Q,K staged transposed ([d][tok]) for conflict-free S-tile inner product.
// ---------------------------------------------------------------------------
__global__ __launch_bounds__(256) void k_attn(const float* __restrict__ qsrc,
                                              const float* __restrict__ ksrc,
                                              const float* __restrict__ vsrc,
                                              const float* __restrict__ mask,
                                              float* __restrict__ outb)
{
    __shared__ float Qt[64][68];  // [d][n]
    __shared__ float Kt[64][68];  // [d][m]
    __shared__ float Vs[64][68];  // [m][d]
    __shared__ float Ss[64][68];  // [n][m]  (masked S tile)
    __shared__ float Rs[16][66];  // partial rowsums [tx][n]
    __shared__ float Zs[64];
    const int tid = threadIdx.x;
    const int ty = tid >> 4, tx = tid & 15;
    const int n0 = blockIdx.x * 64;
    const int bh = blockIdx.y;
    const int b = bh / H_, h = bh % H_;
    const size_t base = (size_t)b * N_ * C_ + (size_t)h * D_;

    // stage Q tile transposed (once)
    for (int i = tid; i < 64 * 16; i += 256) {
        const int t_ = i >> 4, f = (i & 15) * 4;
        float4 qv = *reinterpret_cast<const float4*>(&qsrc[base + (size_t)(n0 + t_) * C_ + f]);
        Qt[f + 0][t_] = qv.x;
        Qt[f + 1][t_] = qv.y;
        Qt[f + 2][t_] = qv.z;
        Qt[f + 3][t_] = qv.w;
    }

    float acc[4][4] = {};
    float racc[4] = {};

    for (int m0 = 0; m0 < N_; m0 += 64) {
        __syncthreads();  // guard Vs/Kt vs previous phase B
        for (int i = tid; i < 64 * 16; i += 256) {
            const int t_ = i >> 4, f = (i & 15) * 4;
            float4 kv = *reinterpret_cast<const float4*>(&ksrc[base + (size_t)(m0 + t_) * C_ + f]);
            Kt[f + 0][t_] = kv.x;
            Kt[f + 1][t_] = kv.y;
            Kt[f + 2][t_] = kv.z;
            Kt[f + 3][t_] = kv.w;
            float4 vv = *reinterpret_cast<const float4*>(&vsrc[base + (size_t)(m0 + t_) * C_ + f]);
            *reinterpret_cast<float4*>(&Vs[t_][f]) = vv;
        }
        __syncthreads();

        // phase A: S tile = Q K^T (inner product over d)
        float s[4][4] = {};
#pragma unroll 8
        for (int d = 0; d < 64; ++d) {
            float4 av = *reinterpret_cast<const float4*>(&Qt[d][ty * 4]);
            float4 bv = *reinterpret_cast<const float4*>(&Kt[d][tx * 4]);
            float a_[4] = {av.x, av.y, av.z, av.w};
            float b_[4] = {bv.x, bv.y, bv.z, bv.w};
#pragma unroll
            for (int i = 0; i < 4; ++i)
#pragma unroll
                for (int j = 0; j < 4; ++j)
                    s[i][j] = fmaf(a_[i], b_[j], s[i][j]);
        }
        // mask multiply + rowsum partials + stash to LDS
#pragma unroll
        for (int i = 0; i < 4; ++i) {
            const float* mrow = &mask[(size_t)(n0 + ty * 4 + i) * N_ + m0 + tx * 4];
#pragma unroll
            for (int j = 0; j < 4; ++j) {
                const float sm = s[i][j] * mrow[j];
                Ss[ty * 4 + i][tx * 4 + j] = sm;
                racc[i] += sm;
            }
        }
        __syncthreads();

        // phase B: acc += Ss @ Vs
#pragma unroll 8
        for (int m = 0; m < 64; ++m) {
            float4 vv = *reinterpret_cast<const float4*>(&Vs[m][tx * 4]);
            float b_[4] = {vv.x, vv.y, vv.z, vv.w};
            float a_[4];
#pragma unroll
            for (int i = 0; i < 4; ++i) a_[i] = Ss[ty * 4 + i][m];
#pragma unroll
            for (int i = 0; i < 4; ++i)
#pragma unroll
                for (int j = 0; j < 4; ++j)
                    acc[i][j] = fmaf(a_[i], b_[j], acc[i][j]);
        }
    }

    // reduce rowsums across tx, compute z
#pragma unroll
    for (int i = 0; i < 4; ++i) Rs[tx][ty * 4 + i] = racc[i];
    __syncthreads();
    if (tid < 64) {
        float ssum = 0.f;
#pragma unroll
        for (int x2 = 0; x2 < 16; ++x2) ssum += Rs[x2][tid];
        Zs[tid] = 1.f / (ssum + EPS_);
    }
    __syncthreads();

#pragma unroll
    for (int i = 0; i < 4; ++i) {
        const float z = Zs[ty * 4 + i];
        float4 o;
        o.x = acc[i][0] * z;
        o.y = acc[i][1] * z;
        o.z = acc[i][2] * z;
        o.w = acc[i][3] * z;
        *reinterpret_cast<float4*>(&outb[base + (size_t)(n0 + ty * 4 + i) * C_ + tx * 4]) = o;
    }
}

// ---------------------------------------------------------------------------
// Stage 5: out = attn @ w_out + b_out
// ---------------------------------------------------------------------------
__global__ __launch_bounds__(256) void k_out(const float* __restrict__ a,
                                             const float* __restrict__ w,
                                             const float* __restrict__ bias,
                                             float* __restrict__ out)
{
    __shared__ float As[16][68];
    __shared__ float Bs[16][68];
    const int tid = threadIdx.x;
    const int ty = tid >> 4, tx = tid & 15;
    const int m0 = blockIdx.y * 64;
    const int n0 = blockIdx.x * 64;
    const int lrA = tid >> 2, lqA = (tid & 3) * 4;
    const int lrB = tid >> 4, lcB = (tid & 15) * 4;
    float acc[4][4] = {};
    for (int k0 = 0; k0 < C_; k0 += 16) {
        float4 a4 = *reinterpret_cast<const float4*>(&a[(size_t)(m0 + lrA) * C_ + k0 + lqA]);
        float4 b4 = *reinterpret_cast<const float4*>(&w[(size_t)(k0 + lrB) * C_ + n0 + lcB]);
        __syncthreads();
        As[lqA + 0][lrA] = a4.x;
        As[lqA + 1][lrA] = a4.y;
        As[lqA + 2][lrA] = a4.z;
        As[lqA + 3][lrA] = a4.w;
        *reinterpret_cast<float4*>(&Bs[lrB][lcB]) = b4;
        __syncthreads();
#pragma unroll
        for (int kk = 0; kk < 16; ++kk) {
            float4 av = *reinterpret_cast<const float4*>(&As[kk][ty * 4]);
            float4 bv = *reinterpret_cast<const float4*>(&Bs[kk][tx * 4]);
            float a_[4] = {av.x, av.y, av.z, av.w};
            float b_[4] = {bv.x, bv.y, bv.z, bv.w};
#pragma unroll
            for (int i = 0; i < 4; ++i)
#pragma unroll
                for (int j = 0; j < 4; ++j)
                    acc[i][j] = fmaf(a_[i], b_[j], acc[i][j]);
        }
    }
#pragma unroll
    for (int i = 0; i < 4; ++i) {
        const int r = m0 + ty * 4 + i;
#pragma unroll
        for (int j = 0; j < 4; ++j) {
            const int c = n0 + tx * 4 + j;
            out[(size_t)r * C_ + c] = acc[i][j] + bias[c];
        }
    }
}

// ---------------------------------------------------------------------------

extern "C" void kernel_launch(void* const* d_in, const int* in_sizes, int n_in,
                              void* d_out, int out_size, void* d_ws, size_t ws_size,
                              hipStream_t stream) {
    (void)in_sizes; (void)n_in; (void)out_size; (void)ws_size;
    const float* x      = (const float*)d_in[0];
    const float* mask   = (const float*)d_in[1];
    const float* w_qkv  = (const float*)d_in[2];
    const float* w_out  = (const float*)d_in[3];
    const float* b_out  = (const float*)d_in[4];
    float* out = (float*)d_out;
    float* ws  = (float*)d_ws;

    const size_t S = (size_t)BN_ * C_;
    float* qb  = ws;          // q' = relu(q)+eps
    float* kb  = ws + S;      // k'
    float* vb  = ws + 2 * S;  // v
    float* qsm = ws + 3 * S;  // q smoothed
    float* ksm = ws + 4 * S;  // k smoothed
    float* attn = qb;         // reuse (q' dead after smoothing)

    dim3 blk(256);
    k_qkv<<<dim3(C3_ / 64, BN_ / 64), blk, 0, stream>>>(x, w_qkv, qb, kb, vb);
    k_smooth<<<dim3(C_ / 64, N_ / 64, B_), blk, 0, stream>>>(mask, qb, qsm);
    k_smooth<<<dim3(C_ / 64, N_ / 64, B_), blk, 0, stream>>>(mask, kb, ksm);
    k_attn<<<dim3(N_ / 64, B_ * H_), blk, 0, stream>>>(qsm, ksm, vb, mask, attn);
    k_out<<<dim3(C_ / 64, BN_ / 64), blk, 0, stream>>>(attn, w_out, b_out, out);
}

// Round 3
// 414.945 us; speedup vs baseline: 3.0265x; 3.0265x over previous
//
#include <hip/hip_runtime.h>

// GRFExactAttention — bf16 MFMA pipeline.
// B=8 N=1024 C=768 H=12 D=64. Inputs/outputs f32; internals bf16 (f32 accum).
//
// Math plan:
//  qkvT[2304][8192] = w_qkvT @ xT     (NT GEMM: A=w_qkvT[2304][768], B'=x[8192][768])
//       rows 0..767=q' (relu+eps), 768..1535=k' (relu+eps), 1536..2303=v
//  qks[b][1024][1536] = M' @ q'k'     (M'[m][n] = 0.1*mask[n][m] + I; A shared over b)
//  attn[b*1024+n][h*64+d] = z_n * sum_m (q_s[n]·k_s[m]) * mask[n][m] * v[m][d]
//  out = attn @ w_out + b_out

typedef unsigned short u16;
typedef __attribute__((ext_vector_type(8))) short short8;
typedef __attribute__((ext_vector_type(4))) float f32x4;

#define MFMA(a, b, c) __builtin_amdgcn_mfma_f32_16x16x32_bf16((a), (b), (c), 0, 0, 0)

__device__ __forceinline__ u16 f2b(float f) {  // f32 -> bf16 RNE
    unsigned u = __builtin_bit_cast(unsigned, f);
    return (u16)((u + 0x7FFFu + ((u >> 16) & 1u)) >> 16);
}
__device__ __forceinline__ float b2f(u16 h) {
    unsigned u = ((unsigned)h) << 16;
    return __builtin_bit_cast(float, u);
}

// ---------------------------------------------------------------------------
// elementwise f32 -> bf16
// ---------------------------------------------------------------------------
__global__ __launch_bounds__(256) void k_conv(const float* __restrict__ in,
                                              u16* __restrict__ out, int n) {
    int i = (blockIdx.x * 256 + threadIdx.x) * 4;
    if (i + 3 < n) {
        float4 v = *reinterpret_cast<const float4*>(&in[i]);
        ushort4 o;
        o.x = f2b(v.x); o.y = f2b(v.y); o.z = f2b(v.z); o.w = f2b(v.w);
        *reinterpret_cast<ushort4*>(&out[i]) = o;
    }
}

// ---------------------------------------------------------------------------
// transpose-convert: out[c][r] = bf16(in[r][c]*alpha + (r==c)*delta)
// in: [R][Cc] f32 ; out: [Cc][R] bf16. Grid (Cc/32, R/32), 256 thr.
// ---------------------------------------------------------------------------
__global__ __launch_bounds__(256) void k_transconv(const float* __restrict__ in,
                                                   u16* __restrict__ out,
                                                   int R, int Cc, float alpha, float delta) {
    __shared__ float t[32][33];
    const int tx = threadIdx.x & 31, ty = threadIdx.x >> 5;  // ty 0..7
    const int r0 = blockIdx.y * 32, c0 = blockIdx.x * 32;
#pragma unroll
    for (int k = 0; k < 4; ++k)
        t[ty + 8 * k][tx] = in[(long)(r0 + ty + 8 * k) * Cc + c0 + tx];
    __syncthreads();
#pragma unroll
    for (int k = 0; k < 4; ++k) {
        const int c = c0 + ty + 8 * k, r = r0 + tx;
        float v = t[tx][ty + 8 * k] * alpha + ((r == c) ? delta : 0.f);
        out[(long)c * R + r] = f2b(v);
    }
}

// ---------------------------------------------------------------------------
// bf16 NT GEMM: C[M][N] = A[M][K] * B'[N][K]^T ; 128x128 tile, BK=32, 4 waves.
// MODE 0: relu+eps rows<1536, bf16 out (qkvT)
// MODE 1: bf16 out, per-z offsets (smoothing)
// MODE 2: f32 out + bias (final)
// ---------------------------------------------------------------------------
template <int MODE>
__global__ __launch_bounds__(256) void k_gemm(const u16* __restrict__ A,
                                              const u16* __restrict__ Bm,
                                              void* __restrict__ Cv,
                                              const float* __restrict__ bias,
                                              int M, int N, int K,
                                              int lda, int ldb, int ldc,
                                              long boffB, long boffC) {
    __shared__ u16 As[128][40];
    __shared__ u16 Bs[128][40];
    const int tid = threadIdx.x;
    const int lane = tid & 63, wid = tid >> 6;
    const int lo = lane & 15, hi = lane >> 4;
    const int wr = wid >> 1, wc = wid & 1;
    const int m0 = blockIdx.y * 128, n0 = blockIdx.x * 128;
    const u16* Bz = Bm + (long)blockIdx.z * boffB;
    const int srow = tid >> 1, skoff = (tid & 1) * 16;  // 32B staged per thread
    const u16* Ag = A + (long)(m0 + srow) * lda + skoff;
    const u16* Bg = Bz + (long)(n0 + srow) * ldb + skoff;

    f32x4 acc[4][4] = {};
    for (int k0 = 0; k0 < K; k0 += 32) {
        short8 a0 = *reinterpret_cast<const short8*>(Ag + k0);
        short8 a1 = *reinterpret_cast<const short8*>(Ag + k0 + 8);
        short8 b0 = *reinterpret_cast<const short8*>(Bg + k0);
        short8 b1 = *reinterpret_cast<const short8*>(Bg + k0 + 8);
        __syncthreads();
        *reinterpret_cast<short8*>(&As[srow][skoff]) = a0;
        *reinterpret_cast<short8*>(&As[srow][skoff + 8]) = a1;
        *reinterpret_cast<short8*>(&Bs[srow][skoff]) = b0;
        *reinterpret_cast<short8*>(&Bs[srow][skoff + 8]) = b1;
        __syncthreads();
        short8 af[4], bf_[4];
#pragma unroll
        for (int i = 0; i < 4; ++i)
            af[i] = *reinterpret_cast<const short8*>(&As[wr * 64 + i * 16 + lo][hi * 8]);
#pragma unroll
        for (int j = 0; j < 4; ++j)
            bf_[j] = *reinterpret_cast<const short8*>(&Bs[wc * 64 + j * 16 + lo][hi * 8]);
#pragma unroll
        for (int i = 0; i < 4; ++i)
#pragma unroll
            for (int j = 0; j < 4; ++j)
                acc[i][j] = MFMA(af[i], bf_[j], acc[i][j]);
    }

#pragma unroll
    for (int i = 0; i < 4; ++i)
#pragma unroll
        for (int j = 0; j < 4; ++j)
#pragma unroll
            for (int r = 0; r < 4; ++r) {
                const int m = m0 + wr * 64 + i * 16 + hi * 4 + r;
                const int n = n0 + wc * 64 + j * 16 + lo;
                float v = acc[i][j][r];
                if (MODE == 0) {
                    if (m < 1536) v = fmaxf(v, 0.f) + 1e-6f;
                    ((u16*)Cv)[(long)m * ldc + n] = f2b(v);
                } else if (MODE == 1) {
                    u16* Cz = (u16*)Cv + (long)blockIdx.z * boffC;
                    Cz[(long)m * ldc + n] = f2b(v);
                } else {
                    ((float*)Cv)[(long)m * ldc + n] = v + bias[n];
                }
            }
}

// ---------------------------------------------------------------------------
// Fused masked linear attention. Block = 64 q-rows of one (b,h); 4 waves,
// wave w owns q-rows [w*16, w*16+16). QK^T and PV via MFMA; mask-mult,
// rowsum, z in f32. S tile passes through per-wave LDS as bf16.
// ---------------------------------------------------------------------------
__global__ __launch_bounds__(256) void k_attn2(const u16* __restrict__ qks,
                                               const u16* __restrict__ qkvT,
                                               const float* __restrict__ mask,
                                               u16* __restrict__ attn) {
    __shared__ u16 Sb[4][16][72];
    const int tid = threadIdx.x, wid = tid >> 6, lane = tid & 63;
    const int lo = lane & 15, hi = lane >> 4;
    const int n0 = blockIdx.x * 64;
    const int bh = blockIdx.y, b = bh / 12, h = bh % 12;
    const long qbase = (long)b * 1024 * 1536;
    const int nA = n0 + wid * 16 + lo;

    short8 aq[2];
#pragma unroll
    for (int kd = 0; kd < 2; ++kd)
        aq[kd] = *reinterpret_cast<const short8*>(
            &qks[qbase + (long)nA * 1536 + h * 64 + kd * 32 + hi * 8]);

    f32x4 oacc[4] = {};
    float racc[4] = {0.f, 0.f, 0.f, 0.f};
    const long vrowbase = (long)(1536 + h * 64) * 8192 + b * 1024;

    for (int m0 = 0; m0 < 1024; m0 += 64) {
        // QK^T
        f32x4 s[4];
#pragma unroll
        for (int jm = 0; jm < 4; ++jm) {
            const long kr = qbase + (long)(m0 + jm * 16 + lo) * 1536 + 768 + h * 64;
            f32x4 sj = {};
            sj = MFMA(aq[0], *reinterpret_cast<const short8*>(&qks[kr + hi * 8]), sj);
            sj = MFMA(aq[1], *reinterpret_cast<const short8*>(&qks[kr + 32 + hi * 8]), sj);
            s[jm] = sj;
        }
        // mask multiply (f32), rowsum accumulate, stash bf16 to per-wave LDS
#pragma unroll
        for (int jm = 0; jm < 4; ++jm) {
            const int mc = m0 + jm * 16 + lo;
#pragma unroll
            for (int r = 0; r < 4; ++r) {
                const int nr = n0 + wid * 16 + hi * 4 + r;
                const float sm = s[jm][r] * mask[(long)nr * 1024 + mc];
                const u16 hb = f2b(sm);
                racc[r] += b2f(hb);  // denominator uses exactly the rounded weights
                Sb[wid][hi * 4 + r][jm * 16 + lo] = hb;
            }
        }
        __syncthreads();
        // PV: oacc[jd] += S_bf(16n x 64m) @ vT(64m x 64d)
#pragma unroll
        for (int km = 0; km < 2; ++km) {
            const short8 as_ =
                *reinterpret_cast<const short8*>(&Sb[wid][lo][km * 32 + hi * 8]);
#pragma unroll
            for (int jd = 0; jd < 4; ++jd) {
                const short8 bv = *reinterpret_cast<const short8*>(
                    &qkvT[vrowbase + (long)(jd * 16 + lo) * 8192 + m0 + km * 32 + hi * 8]);
                oacc[jd] = MFMA(as_, bv, oacc[jd]);
            }
        }
    }

    // rowsum: reduce over the 16 column-lanes (low 4 lane bits), then z
#pragma unroll
    for (int r = 0; r < 4; ++r) {
        float v = racc[r];
        v += __shfl_xor(v, 1);
        v += __shfl_xor(v, 2);
        v += __shfl_xor(v, 4);
        v += __shfl_xor(v, 8);
        racc[r] = 1.f / (v + 1e-6f);
    }
    const long obase = (long)(b * 1024) * 768 + h * 64;
#pragma unroll
    for (int jd = 0; jd < 4; ++jd)
#pragma unroll
        for (int r = 0; r < 4; ++r) {
            const int nr = n0 + wid * 16 + hi * 4 + r;
            attn[obase + (long)nr * 768 + jd * 16 + lo] = f2b(oacc[jd][r] * racc[r]);
        }
}

// ---------------------------------------------------------------------------

extern "C" void kernel_launch(void* const* d_in, const int* in_sizes, int n_in,
                              void* d_out, int out_size, void* d_ws, size_t ws_size,
                              hipStream_t stream) {
    (void)in_sizes; (void)n_in; (void)out_size; (void)ws_size;
    const float* x     = (const float*)d_in[0];
    const float* mask  = (const float*)d_in[1];
    const float* w_qkv = (const float*)d_in[2];
    const float* w_out = (const float*)d_in[3];
    const float* b_out = (const float*)d_in[4];
    float* out = (float*)d_out;

    u16* ws = (u16*)d_ws;  // element (2B) offsets
    u16* xb     = ws;                       // [8192][768]
    u16* wqkvT  = xb + (size_t)8192 * 768;  // [2304][768]
    u16* mTb    = wqkvT + (size_t)2304 * 768;   // [1024][1024]
    u16* woutT  = mTb + (size_t)1024 * 1024;    // [768][768]
    u16* qkvT   = woutT + (size_t)768 * 768;    // [2304][8192]
    u16* qks    = qkvT + (size_t)2304 * 8192;   // [8][1024][1536]
    u16* attnb  = qks + (size_t)8192 * 1536;    // [8192][768]

    // conversions / transposes
    k_conv<<<dim3(6144), dim3(256), 0, stream>>>(x, xb, 8192 * 768);
    k_transconv<<<dim3(72, 24), dim3(256), 0, stream>>>(w_qkv, wqkvT, 768, 2304, 1.f, 0.f);
    k_transconv<<<dim3(32, 32), dim3(256), 0, stream>>>(mask, mTb, 1024, 1024, 0.1f, 1.f);
    k_transconv<<<dim3(24, 24), dim3(256), 0, stream>>>(w_out, woutT, 768, 768, 1.f, 0.f);

    // qkvT = w_qkvT @ xT (relu+eps on q,k rows)
    k_gemm<0><<<dim3(64, 18, 1), dim3(256), 0, stream>>>(
        wqkvT, xb, qkvT, nullptr, 2304, 8192, 768, 768, 768, 8192, 0, 0);
    // qks[b] = M' @ [q'|k']  (per batch)
    k_gemm<1><<<dim3(12, 8, 8), dim3(256), 0, stream>>>(
        mTb, qkvT, qks, nullptr, 1024, 1536, 1024, 1024, 8192, 1536,
        1024L, 1024L * 1536L);
    // fused attention
    k_attn2<<<dim3(16, 96), dim3(256), 0, stream>>>(qks, qkvT, mask, attnb);
    // out = attn @ w_out + b_out
    k_gemm<2><<<dim3(6, 64, 1), dim3(256), 0, stream>>>(
        attnb, woutT, out, b_out, 8192, 768, 768, 768, 768, 768, 0, 0);
}